// Round 8
// baseline (179.016 us; speedup 1.0000x reference)
//
#include <hip/hip_runtime.h>

#define BATCH 512
#define SEQ   512
#define VOCAB 1000
#define EMB   100
#define UNITS 64
#define SC    2.88539008177792681f   // 2*log2(e): v_exp_f32(SC*s) == e^{2s}

typedef float v2f __attribute__((ext_vector_type(2)));

// ---------------------------------------------------------------------------
// Kernel 1: P[v][u] = SC*( (emb[v]@Wxh)[u] + b[u] + colsum(Whh)[u] )
// colsum fold supports the r-recurrence: y = x + W.h, h = 1-2r
//   =>  y = (x + W.1) - 2*W.r  -- the per-step h=fma(-2,r,1) vanishes.
// ---------------------------------------------------------------------------
__global__ __launch_bounds__(64) void proj_kernel(
    const float* __restrict__ emb, const float* __restrict__ Wxh,
    const float* __restrict__ bias, const float* __restrict__ Whh,
    float* __restrict__ P) {
  const int v = blockIdx.x;
  const int u = threadIdx.x;
  const float* e = emb + v * EMB;
  float acc = bias[u];
#pragma unroll 5
  for (int d = 0; d < EMB; ++d) acc += e[d] * Wxh[d * UNITS + u];
  float csum = 0.f;
#pragma unroll 8
  for (int i = 0; i < UNITS; ++i) csum += Whh[i * UNITS + u];
  P[v * UNITS + u] = SC * (acc + csum);
}

// ---------------------------------------------------------------------------
// DPP all-gather across the lane's own 16-lane row; slot->source permutation
// calibrated at runtime on lane_id and folded into the weight layout.
// ---------------------------------------------------------------------------
#define DPP_I(src, ctrl) __builtin_amdgcn_update_dpp(0, (src), (ctrl), 0xF, 0xF, true)

#define GATHER_ROW(v_, g_)                                          \
  do {                                                              \
    g_[0] = DPP_I((v_), 0x00);  g_[1] = DPP_I((v_), 0x55);          \
    g_[2] = DPP_I((v_), 0xAA);  g_[3] = DPP_I((v_), 0xFF);          \
    g_[4]  = DPP_I(g_[0], 0x124); g_[5]  = DPP_I(g_[1], 0x124);     \
    g_[6]  = DPP_I(g_[2], 0x124); g_[7]  = DPP_I(g_[3], 0x124);     \
    g_[8]  = DPP_I(g_[0], 0x128); g_[9]  = DPP_I(g_[1], 0x128);     \
    g_[10] = DPP_I(g_[2], 0x128); g_[11] = DPP_I(g_[3], 0x128);     \
    g_[12] = DPP_I(g_[0], 0x12C); g_[13] = DPP_I(g_[1], 0x12C);     \
    g_[14] = DPP_I(g_[2], 0x12C); g_[15] = DPP_I(g_[3], 0x12C);     \
  } while (0)

// Two-row interleaved gather: B's DPPs sit in A's DPP->DPP hazard gaps.
#define GATHER2(vA_, gA_, vB_, gB_)                                          \
  do {                                                                       \
    gA_[0] = DPP_I((vA_), 0x00);  gB_[0] = DPP_I((vB_), 0x00);               \
    gA_[1] = DPP_I((vA_), 0x55);  gB_[1] = DPP_I((vB_), 0x55);               \
    gA_[2] = DPP_I((vA_), 0xAA);  gB_[2] = DPP_I((vB_), 0xAA);               \
    gA_[3] = DPP_I((vA_), 0xFF);  gB_[3] = DPP_I((vB_), 0xFF);               \
    gA_[4]  = DPP_I(gA_[0], 0x124); gB_[4]  = DPP_I(gB_[0], 0x124);          \
    gA_[5]  = DPP_I(gA_[1], 0x124); gB_[5]  = DPP_I(gB_[1], 0x124);          \
    gA_[6]  = DPP_I(gA_[2], 0x124); gB_[6]  = DPP_I(gB_[2], 0x124);          \
    gA_[7]  = DPP_I(gA_[3], 0x124); gB_[7]  = DPP_I(gB_[3], 0x124);          \
    gA_[8]  = DPP_I(gA_[0], 0x128); gB_[8]  = DPP_I(gB_[0], 0x128);          \
    gA_[9]  = DPP_I(gA_[1], 0x128); gB_[9]  = DPP_I(gB_[1], 0x128);          \
    gA_[10] = DPP_I(gA_[2], 0x128); gB_[10] = DPP_I(gB_[2], 0x128);          \
    gA_[11] = DPP_I(gA_[3], 0x128); gB_[11] = DPP_I(gB_[3], 0x128);          \
    gA_[12] = DPP_I(gA_[0], 0x12C); gB_[12] = DPP_I(gB_[0], 0x12C);          \
    gA_[13] = DPP_I(gA_[1], 0x12C); gB_[13] = DPP_I(gB_[1], 0x12C);          \
    gA_[14] = DPP_I(gA_[2], 0x12C); gB_[14] = DPP_I(gB_[2], 0x12C);          \
    gA_[15] = DPP_I(gA_[3], 0x12C); gB_[15] = DPP_I(gB_[3], 0x12C);          \
  } while (0)

// lane^16 / lane^32 exchange. NON-volatile in the loop: only data deps
// constrain the scheduler, so the two rows' combines interleave (r2's
// volatile version force-serialized them). s_nop guards the VALU->permlane
// wait states (hazard recognizer can't see inside asm).
__device__ __forceinline__ float sw16(float v, bool sel) {
  int x = __float_as_int(v), y = x;
  asm("s_nop 1\n\tv_permlane16_swap_b32 %0, %1" : "+v"(x), "+v"(y));
  return sel ? __int_as_float(x) : __int_as_float(y);
}
__device__ __forceinline__ float sw32(float v, bool sel) {
  int x = __float_as_int(v), y = x;
  asm("s_nop 1\n\tv_permlane32_swap_b32 %0, %1" : "+v"(x), "+v"(y));
  return sel ? __int_as_float(x) : __int_as_float(y);
}

// ---------------------------------------------------------------------------
// Kernel 2: sequential scan on r(t) = 1/(e^{2s}+1). TWO rows per wave,
// SOURCE-INTERLEAVED: row B's ~73 instructions fill row A's in-order hazard
// bubbles (DPP waits, combine tail, trans latency) -- statically schedulable
// since all latencies are compiler-known. Flat t-loop with unroll 8 keeps
// the body ~10KB = icache-resident (r6's full unroll streamed ~300KB of
// straight-line code through L2 every step). Tokens come from a uniform
// scalar-load ring (dist-2), eliminating the tokv VGPR arrays + readlanes.
// ---------------------------------------------------------------------------
__global__ __launch_bounds__(64)
__attribute__((amdgpu_waves_per_eu(1, 1)))
void scan_kernel(
    const int* __restrict__ tok, const float* __restrict__ P,
    const float* __restrict__ Whh, const float* __restrict__ Wout,
    const float* __restrict__ bout, float* __restrict__ out) {
  const int lane = threadIdx.x;
  const int rowA = blockIdx.x * 2;
  const int rowB = rowA + 1;

  // ---- calibration: gather permutation + swap register-select ----
  int gcal[16];
  GATHER_ROW(lane, gcal);  // gcal[s] = source lane (== unit index) of slot s

  int x16 = lane, y16 = lane;
  asm volatile("s_nop 1\n\tv_permlane16_swap_b32 %0, %1" : "+v"(x16), "+v"(y16));
  const bool sel16 = (x16 == (lane ^ 16));
  int x32 = lane, y32 = lane;
  asm volatile("s_nop 1\n\tv_permlane32_swap_b32 %0, %1" : "+v"(x32), "+v"(y32));
  const bool sel32 = (x32 == (lane ^ 32));

  // ---- weights: 4 columns (lane, ^16, ^32, ^48) x own-row 16 inputs,
  // permuted to gather order, scaled by -2*SC (r-recurrence), pinned;
  // SHARED by both rows ----
  const int c0 = lane, c1 = lane ^ 16, c2 = lane ^ 32, c3 = lane ^ 48;
  v2f w0[8], w1[8], w2[8], w3[8];
#pragma unroll
  for (int s = 0; s < 8; ++s) {
    const int i0 = gcal[2 * s] * UNITS, i1 = gcal[2 * s + 1] * UNITS;
    float t00 = -2.f * SC * Whh[i0 + c0], t01 = -2.f * SC * Whh[i1 + c0];
    float t10 = -2.f * SC * Whh[i0 + c1], t11 = -2.f * SC * Whh[i1 + c1];
    float t20 = -2.f * SC * Whh[i0 + c2], t21 = -2.f * SC * Whh[i1 + c2];
    float t30 = -2.f * SC * Whh[i0 + c3], t31 = -2.f * SC * Whh[i1 + c3];
    asm volatile("" : "+v"(t00), "+v"(t01), "+v"(t10), "+v"(t11));
    asm volatile("" : "+v"(t20), "+v"(t21), "+v"(t30), "+v"(t31));
    w0[s].x = t00; w0[s].y = t01;  w1[s].x = t10; w1[s].y = t11;
    w2[s].x = t20; w2[s].y = t21;  w3[s].x = t30; w3[s].y = t31;
  }

  const int* trA = tok + (long)rowA * SEQ;
  const int* trB = tok + (long)rowB * SEQ;

  float rr_A = 0.5f, rr_B = 0.5f;  // h = 0  <=>  r = 0.5

  // Uniform token ring (scalar loads): tk*c = token(t+2) at iter t.
  int tkAc = trA[2], tkAn = trA[3];
  int tkBc = trB[2], tkBn = trB[3];
  // P-value ring: a0 = row(t), a1 = row(t+1).
  float a0A = P[(long)trA[0] * UNITS + lane];
  float a1A = P[(long)trA[1] * UNITS + lane];
  float a0B = P[(long)trB[0] * UNITS + lane];
  float a1B = P[(long)trB[1] * UNITS + lane];

#pragma unroll 8
  for (int t = 0; t < SEQ; ++t) {
    float aCA = a0A; a0A = a1A;
    float aCB = a0B; a0B = a1B;
    a1A = P[(long)tkAc * UNITS + lane];   // row t+2 (dist-2: latency covered)
    a1B = P[(long)tkBc * UNITS + lane];
    const int nidx = (t + 4 < SEQ) ? t + 4 : SEQ - 1;  // uniform clamp
    tkAc = tkAn; tkAn = trA[nidx];
    tkBc = tkBn; tkBn = trB[nidx];

    // ---- interleaved in-register all-gather (A fills B's DPP gaps) ----
    int giA[16], giB[16];
    GATHER2(__float_as_int(rr_A), giA, __float_as_int(rr_B), giB);

    // ---- interleaved 4-partial pk_fma blocks (8-deep chains; A/B
    // alternating gives every fma a >=2-instr gap to its producer) ----
    v2f qA0, qA1 = {0.f, 0.f}, qA2 = {0.f, 0.f}, qA3 = {0.f, 0.f};
    v2f qB0, qB1 = {0.f, 0.f}, qB2 = {0.f, 0.f}, qB3 = {0.f, 0.f};
    qA0.x = aCA; qA0.y = 0.f;
    qB0.x = aCB; qB0.y = 0.f;
#pragma unroll
    for (int s = 0; s < 8; ++s) {
      v2f gA, gB;
      gA.x = __int_as_float(giA[2 * s]);
      gA.y = __int_as_float(giA[2 * s + 1]);
      gB.x = __int_as_float(giB[2 * s]);
      gB.y = __int_as_float(giB[2 * s + 1]);
      qA0 += gA * w0[s];  qB0 += gB * w0[s];
      qA1 += gA * w1[s];  qB1 += gB * w1[s];
      qA2 += gA * w2[s];  qB2 += gB * w2[s];
      qA3 += gA * w3[s];  qB3 += gB * w3[s];
    }
    float pA0 = qA0.x + qA0.y, pB0 = qB0.x + qB0.y;
    float pA1 = qA1.x + qA1.y, pB1 = qB1.x + qB1.y;
    float pA2 = qA2.x + qA2.y, pB2 = qB2.x + qB2.y;
    float pA3 = qA3.x + qA3.y, pB3 = qB3.x + qB3.y;

    // ---- interleaved combines (non-volatile: scheduler may interleave) ----
    float s1A = pA0 + sw16(pA1, sel16);
    float s1B = pB0 + sw16(pB1, sel16);
    float s2A = pA2 + sw16(pA3, sel16);
    float s2B = pB2 + sw16(pB3, sel16);
    float yA = s1A + sw32(s2A, sel32);
    float yB = s1B + sw32(s2B, sel32);

    // r = 1/(e^{2s}+1);  e^{2s} = 2^yv (SC prescale). Trans latencies of
    // row A covered by row B's tail and the next iteration's loads.
    float exA; asm("v_exp_f32 %0, %1" : "=v"(exA) : "v"(yA));
    float exB; asm("v_exp_f32 %0, %1" : "=v"(exB) : "v"(yB));
    rr_A = __builtin_amdgcn_rcpf(exA + 1.f);
    rr_B = __builtin_amdgcn_rcpf(exB + 1.f);
  }

  // h = 1 - 2r; out[row] = sigmoid(sum_j h[j]*Wout[j] + bout)
  float hA = __builtin_fmaf(-2.f, rr_A, 1.f);
  float hB = __builtin_fmaf(-2.f, rr_B, 1.f);
  float wl = Wout[lane];
  float pA = hA * wl;
  float pB = hB * wl;
#pragma unroll
  for (int off = 32; off > 0; off >>= 1) {
    pA += __shfl_xor(pA, off);
    pB += __shfl_xor(pB, off);
  }
  if (lane == 0) {
    float b0 = bout[0];
    out[rowA] = 1.f / (1.f + __expf(-(pA + b0)));
    out[rowB] = 1.f / (1.f + __expf(-(pB + b0)));
  }
}

extern "C" void kernel_launch(void* const* d_in, const int* in_sizes, int n_in,
                              void* d_out, int out_size, void* d_ws, size_t ws_size,
                              hipStream_t stream) {
  const int*   tok  = (const int*)  d_in[0];  // [BATCH, SEQ] int32
  const float* emb  = (const float*)d_in[1];  // [VOCAB, EMB]
  const float* Wxh  = (const float*)d_in[2];  // [EMB, UNITS]
  const float* Whh  = (const float*)d_in[3];  // [UNITS, UNITS]
  const float* bias = (const float*)d_in[4];  // [UNITS]
  const float* Wout = (const float*)d_in[5];  // [UNITS, 1]
  const float* bout = (const float*)d_in[6];  // [1]
  float* out = (float*)d_out;                 // [BATCH, 1] fp32

  float* P = (float*)d_ws;                    // VOCAB*UNITS fp32 = 256 KB

  proj_kernel<<<VOCAB, 64, 0, stream>>>(emb, Wxh, bias, Whh, P);
  scan_kernel<<<BATCH / 2, 64, 0, stream>>>(tok, P, Whh, Wout, bout, out);
}

// Round 9
// 102.843 us; speedup vs baseline: 1.7407x; 1.7407x over previous
//
#include <hip/hip_runtime.h>

#define BATCH 512
#define SEQ   512
#define VOCAB 1000
#define EMB   100
#define UNITS 64
#define SC    2.88539008177792681f   // 2*log2(e): v_exp_f32(SC*s) == e^{2s}

typedef float v2f __attribute__((ext_vector_type(2)));

// ---------------------------------------------------------------------------
// Kernel 1: P[v][u] = SC*( (emb[v]@Wxh)[u] + b[u] + colsum(Whh)[u] )
// colsum fold supports the r-recurrence: y = x + W.h, h = 1-2r
//   =>  y = (x + W.1) - 2*W.r  -- the per-step h=fma(-2,r,1) vanishes.
// ---------------------------------------------------------------------------
__global__ __launch_bounds__(64) void proj_kernel(
    const float* __restrict__ emb, const float* __restrict__ Wxh,
    const float* __restrict__ bias, const float* __restrict__ Whh,
    float* __restrict__ P) {
  const int v = blockIdx.x;
  const int u = threadIdx.x;
  const float* e = emb + v * EMB;
  float acc = bias[u];
#pragma unroll 5
  for (int d = 0; d < EMB; ++d) acc += e[d] * Wxh[d * UNITS + u];
  float csum = 0.f;
#pragma unroll 8
  for (int i = 0; i < UNITS; ++i) csum += Whh[i * UNITS + u];
  P[v * UNITS + u] = SC * (acc + csum);
}

// ---------------------------------------------------------------------------
// DPP all-gather across the lane's own 16-lane row; slot->source permutation
// calibrated at runtime on lane_id and folded into the weight layout.
// ---------------------------------------------------------------------------
#define DPP_I(src, ctrl) __builtin_amdgcn_update_dpp(0, (src), (ctrl), 0xF, 0xF, true)

#define GATHER_ROW(v_, g_)                                          \
  do {                                                              \
    g_[0] = DPP_I((v_), 0x00);  g_[1] = DPP_I((v_), 0x55);          \
    g_[2] = DPP_I((v_), 0xAA);  g_[3] = DPP_I((v_), 0xFF);          \
    g_[4]  = DPP_I(g_[0], 0x124); g_[5]  = DPP_I(g_[1], 0x124);     \
    g_[6]  = DPP_I(g_[2], 0x124); g_[7]  = DPP_I(g_[3], 0x124);     \
    g_[8]  = DPP_I(g_[0], 0x128); g_[9]  = DPP_I(g_[1], 0x128);     \
    g_[10] = DPP_I(g_[2], 0x128); g_[11] = DPP_I(g_[3], 0x128);     \
    g_[12] = DPP_I(g_[0], 0x12C); g_[13] = DPP_I(g_[1], 0x12C);     \
    g_[14] = DPP_I(g_[2], 0x12C); g_[15] = DPP_I(g_[3], 0x12C);     \
  } while (0)

// lane^16 / lane^32 exchange (r4/r6-proven form: duplicate, swap, select).
__device__ __forceinline__ float sw16(float v, bool sel) {
  int x = __float_as_int(v), y = x;
  asm volatile("s_nop 1\n\tv_permlane16_swap_b32 %0, %1" : "+v"(x), "+v"(y));
  return sel ? __int_as_float(x) : __int_as_float(y);
}
__device__ __forceinline__ float sw32(float v, bool sel) {
  int x = __float_as_int(v), y = x;
  asm volatile("s_nop 1\n\tv_permlane32_swap_b32 %0, %1" : "+v"(x), "+v"(y));
  return sel ? __int_as_float(x) : __int_as_float(y);
}

// ---------------------------------------------------------------------------
// Kernel 2: sequential scan on r(t) = 1/(e^{2s}+1). ONE row per wave, math
// identical to r6 (best: 99.5us). SINGLE VARIABLE vs r6: the step body runs
// in a ROLLED loop (unroll 2, ~1.3KB = icache-resident) instead of a 512x
// full unroll (~300KB straight-line code fetched cold from L2 every step --
// the suspected ~300 cyc/step front-end stall that no dep/ILP model could
// explain). Tokens via uniform scalar ring (r8-validated): SALU-pipe loads,
// no tokv VGPR arrays, no per-step readlane; P address is saddr-form
// (scalar base + fixed lane*4 voffset), zero per-step VALU address math.
// ---------------------------------------------------------------------------
__global__ __launch_bounds__(64)
__attribute__((amdgpu_waves_per_eu(1, 1)))
void scan_kernel(
    const int* __restrict__ tok, const float* __restrict__ P,
    const float* __restrict__ Whh, const float* __restrict__ Wout,
    const float* __restrict__ bout, float* __restrict__ out) {
  const int row  = blockIdx.x;
  const int lane = threadIdx.x;

  // ---- calibration: gather permutation + swap register-select ----
  int gcal[16];
  GATHER_ROW(lane, gcal);  // gcal[s] = source lane (== unit index) of slot s

  int x16 = lane, y16 = lane;
  asm volatile("s_nop 1\n\tv_permlane16_swap_b32 %0, %1" : "+v"(x16), "+v"(y16));
  const bool sel16 = (x16 == (lane ^ 16));
  int x32 = lane, y32 = lane;
  asm volatile("s_nop 1\n\tv_permlane32_swap_b32 %0, %1" : "+v"(x32), "+v"(y32));
  const bool sel32 = (x32 == (lane ^ 32));

  // ---- weights: 4 columns (lane, ^16, ^32, ^48) x own-row 16 inputs,
  // permuted to gather order, scaled by -2*SC (r-recurrence), pinned ----
  const int c0 = lane, c1 = lane ^ 16, c2 = lane ^ 32, c3 = lane ^ 48;
  v2f w0[8], w1[8], w2[8], w3[8];
#pragma unroll
  for (int s = 0; s < 8; ++s) {
    const int i0 = gcal[2 * s] * UNITS, i1 = gcal[2 * s + 1] * UNITS;
    float t00 = -2.f * SC * Whh[i0 + c0], t01 = -2.f * SC * Whh[i1 + c0];
    float t10 = -2.f * SC * Whh[i0 + c1], t11 = -2.f * SC * Whh[i1 + c1];
    float t20 = -2.f * SC * Whh[i0 + c2], t21 = -2.f * SC * Whh[i1 + c2];
    float t30 = -2.f * SC * Whh[i0 + c3], t31 = -2.f * SC * Whh[i1 + c3];
    asm volatile("" : "+v"(t00), "+v"(t01), "+v"(t10), "+v"(t11));
    asm volatile("" : "+v"(t20), "+v"(t21), "+v"(t30), "+v"(t31));
    w0[s].x = t00; w0[s].y = t01;  w1[s].x = t10; w1[s].y = t11;
    w2[s].x = t20; w2[s].y = t21;  w3[s].x = t30; w3[s].y = t31;
  }

  const int* trow = tok + (long)row * SEQ;

  float r = 0.5f;  // h = 0  <=>  r = 0.5

  // Uniform token ring (scalar loads): tkc = token(t+2) at iter t.
  int tkc = trow[2], tkn = trow[3];
  // P-value ring: a0 = row(t), a1 = row(t+1).
  float a0 = P[(long)trow[0] * UNITS + lane];
  float a1 = P[(long)trow[1] * UNITS + lane];

#pragma unroll 2
  for (int t = 0; t < SEQ; ++t) {
    float a_cur = a0;
    a0 = a1;
    a1 = P[(long)tkc * UNITS + lane];   // row t+2 (dist-2: latency covered)
    const int nidx = (t + 4 < SEQ) ? t + 4 : SEQ - 1;  // uniform clamp
    tkc = tkn; tkn = trow[nidx];

    // ---- in-register all-gather of r across own 16-lane row ----
    int gi[16];
    GATHER_ROW(__float_as_int(r), gi);

    // ---- 4 column partials, 8-deep pk_fma chains; P' folded into
    // acc0 init; -2*SC folded into weights ----
    v2f acc0, acc1 = {0.f, 0.f}, acc2 = {0.f, 0.f}, acc3 = {0.f, 0.f};
    acc0.x = a_cur; acc0.y = 0.f;
#pragma unroll
    for (int s = 0; s < 8; ++s) {
      v2f gp;
      gp.x = __int_as_float(gi[2 * s]);
      gp.y = __int_as_float(gi[2 * s + 1]);
      acc0 += gp * w0[s];
      acc1 += gp * w1[s];
      acc2 += gp * w2[s];
      acc3 += gp * w3[s];
    }
    float p0 = acc0.x + acc0.y;   // col lane      (incl. a_cur)
    float p1 = acc1.x + acc1.y;   // col lane^16
    float p2 = acc2.x + acc2.y;   // col lane^32
    float p3 = acc3.x + acc3.y;   // col lane^48

    // combine: yv[j] = P0(j) + P1(j^16) + P2(j^32) + P3(j^48) = SC * s(t+1)
    float s1 = p0 + sw16(p1, sel16);
    float s2 = p2 + sw16(p3, sel16);
    float yv = s1 + sw32(s2, sel32);

    // r = 1/(e^{2s}+1);  e^{2s} = 2^yv. Trans ops are HW-interlocked.
    float ex; asm("v_exp_f32 %0, %1" : "=v"(ex) : "v"(yv));
    r = __builtin_amdgcn_rcpf(ex + 1.f);
  }

  // h = 1 - 2r (once); out[row] = sigmoid(sum_j h[j]*Wout[j] + bout)
  float h = __builtin_fmaf(-2.f, r, 1.f);
  float p = h * Wout[lane];
#pragma unroll
  for (int off = 32; off > 0; off >>= 1) p += __shfl_xor(p, off);
  if (lane == 0) out[row] = 1.f / (1.f + __expf(-(p + bout[0])));
}

extern "C" void kernel_launch(void* const* d_in, const int* in_sizes, int n_in,
                              void* d_out, int out_size, void* d_ws, size_t ws_size,
                              hipStream_t stream) {
  const int*   tok  = (const int*)  d_in[0];  // [BATCH, SEQ] int32
  const float* emb  = (const float*)d_in[1];  // [VOCAB, EMB]
  const float* Wxh  = (const float*)d_in[2];  // [EMB, UNITS]
  const float* Whh  = (const float*)d_in[3];  // [UNITS, UNITS]
  const float* bias = (const float*)d_in[4];  // [UNITS]
  const float* Wout = (const float*)d_in[5];  // [UNITS, 1]
  const float* bout = (const float*)d_in[6];  // [1]
  float* out = (float*)d_out;                 // [BATCH, 1] fp32

  float* P = (float*)d_ws;                    // VOCAB*UNITS fp32 = 256 KB

  proj_kernel<<<VOCAB, 64, 0, stream>>>(emb, Wxh, bias, Whh, P);
  scan_kernel<<<BATCH, 64, 0, stream>>>(tok, P, Whh, Wout, bout, out);
}

// Round 10
// 94.274 us; speedup vs baseline: 1.8989x; 1.0909x over previous
//
#include <hip/hip_runtime.h>

#define BATCH 512
#define SEQ   512
#define VOCAB 1000
#define EMB   100
#define UNITS 64
#define SC    2.88539008177792681f   // 2*log2(e): exp2(SC*s) == e^{2s}

typedef float    v2f   __attribute__((ext_vector_type(2)));
typedef unsigned u32x2 __attribute__((ext_vector_type(2)));

// ---------------------------------------------------------------------------
// Kernel 1: P[v][u] = SC*( (emb[v]@Wxh)[u] + b[u] + colsum(Whh)[u] )
// colsum fold supports the r-recurrence: y = x + W.h, h = 1-2r
//   =>  y = (x + W.1) - 2*W.r  -- no per-step h reconstruction in the scan.
// ---------------------------------------------------------------------------
__global__ __launch_bounds__(64) void proj_kernel(
    const float* __restrict__ emb, const float* __restrict__ Wxh,
    const float* __restrict__ bias, const float* __restrict__ Whh,
    float* __restrict__ P) {
  const int v = blockIdx.x;
  const int u = threadIdx.x;
  const float* e = emb + v * EMB;
  float acc = bias[u];
#pragma unroll 5
  for (int d = 0; d < EMB; ++d) acc += e[d] * Wxh[d * UNITS + u];
  float csum = 0.f;
#pragma unroll 8
  for (int i = 0; i < UNITS; ++i) csum += Whh[i * UNITS + u];
  P[v * UNITS + u] = SC * (acc + csum);
}

// ---------------------------------------------------------------------------
// DPP all-gather across the lane's own 16-lane row; slot->source permutation
// calibrated at runtime on lane_id and folded into the weight layout.
// ---------------------------------------------------------------------------
#define DPP_I(src, ctrl) __builtin_amdgcn_update_dpp(0, (src), (ctrl), 0xF, 0xF, true)

#define GATHER_ROW(v_, g_)                                          \
  do {                                                              \
    g_[0] = DPP_I((v_), 0x00);  g_[1] = DPP_I((v_), 0x55);          \
    g_[2] = DPP_I((v_), 0xAA);  g_[3] = DPP_I((v_), 0xFF);          \
    g_[4]  = DPP_I(g_[0], 0x124); g_[5]  = DPP_I(g_[1], 0x124);     \
    g_[6]  = DPP_I(g_[2], 0x124); g_[7]  = DPP_I(g_[3], 0x124);     \
    g_[8]  = DPP_I(g_[0], 0x128); g_[9]  = DPP_I(g_[1], 0x128);     \
    g_[10] = DPP_I(g_[2], 0x128); g_[11] = DPP_I(g_[3], 0x128);     \
    g_[12] = DPP_I(g_[0], 0x12C); g_[13] = DPP_I(g_[1], 0x12C);     \
    g_[14] = DPP_I(g_[2], 0x12C); g_[15] = DPP_I(g_[3], 0x12C);     \
  } while (0)

// Raw permlane swap returning BOTH outputs. Builtin path (scheduler-managed
// hazards, no volatile fence); fallback = r5-proven non-volatile asm.
#if __has_builtin(__builtin_amdgcn_permlane16_swap) && \
    __has_builtin(__builtin_amdgcn_permlane32_swap)
__device__ __forceinline__ u32x2 plswap16(unsigned x, unsigned y) {
  return __builtin_amdgcn_permlane16_swap(x, y, false, false);
}
__device__ __forceinline__ u32x2 plswap32(unsigned x, unsigned y) {
  return __builtin_amdgcn_permlane32_swap(x, y, false, false);
}
#else
__device__ __forceinline__ u32x2 plswap16(unsigned x, unsigned y) {
  asm("s_nop 1\n\tv_permlane16_swap_b32 %0, %1" : "+v"(x), "+v"(y));
  u32x2 r; r.x = x; r.y = y; return r;
}
__device__ __forceinline__ u32x2 plswap32(unsigned x, unsigned y) {
  asm("s_nop 1\n\tv_permlane32_swap_b32 %0, %1" : "+v"(x), "+v"(y));
  u32x2 r; r.x = x; r.y = y; return r;
}
#endif

// Selection-free combine (r5-proven algebra): sum of both swap outputs =
// q_w[l] + q_w[l^N], with the "winning" partial w alternating by lane
// parity -- absorbed into the calibrated weight-column layout below.
__device__ __forceinline__ float swadd16(float vd, float vs) {
  u32x2 p = plswap16((unsigned)__float_as_int(vd), (unsigned)__float_as_int(vs));
  return __int_as_float((int)p.x) + __int_as_float((int)p.y);
}
__device__ __forceinline__ float swadd32(float vd, float vs) {
  u32x2 p = plswap32((unsigned)__float_as_int(vd), (unsigned)__float_as_int(vs));
  return __int_as_float((int)p.x) + __int_as_float((int)p.y);
}

// ---------------------------------------------------------------------------
// Kernel 2: sequential scan on r(t) = 1/(e^{2s}+1), one row per wave.
// Empirical model (fits r1-r9 within ~5%): step = 5.3 cyc x N_instr + ~80.
// This round minimizes N: 16 DPP gather + 32 pk_fma + 4 extract-adds +
// selection-free combine (3 permlane + 3 add, NO cndmask/s_nop) + post-add
// of a + exp2/add/rcp tail, all builtin-scheduled (no volatile fences).
// ---------------------------------------------------------------------------
__global__ __launch_bounds__(64)
__attribute__((amdgpu_waves_per_eu(1, 1)))
void scan_kernel(
    const int* __restrict__ tok, const float* __restrict__ P,
    const float* __restrict__ Whh, const float* __restrict__ Wout,
    const float* __restrict__ bout, float* __restrict__ out) {
  const int row  = blockIdx.x;
  const int lane = threadIdx.x;

  // ---- calibration: gather permutation ----
  int gcal[16];
  GATHER_ROW(lane, gcal);  // gcal[s] = source lane (== unit index) of slot s

  // ---- calibration: swap convention flags F16/F32 (r5-proven probe) ----
  {
    // placeholder scope; probes below
  }
  u32x2 pr16 = plswap16((unsigned)lane, (unsigned)(1000 + lane));
  const int b4  = (lane >> 4) & 1;
  const int F16 = ((((int)pr16.x >= 1000) ? 1 : 0) ^ b4) ? 0 : 1;
  u32x2 pr32 = plswap32((unsigned)lane, (unsigned)(1000 + lane));
  const int b5  = (lane >> 5) & 1;
  const int F32 = ((((int)pr32.x >= 1000) ? 1 : 0) ^ b5) ? 0 : 1;

  // ---- weights: partial (j,k) carries column (lane&15)|((j^F16)<<4)|
  // ((k^F32)<<5) (r5-proven layout), rows permuted to gather order,
  // scaled by -2*SC (r-recurrence), pinned in VGPRs ----
  const int cb  = lane & 15;
  const int c00 = cb | ((0 ^ F16) << 4) | ((0 ^ F32) << 5);
  const int c01 = cb | ((0 ^ F16) << 4) | ((1 ^ F32) << 5);
  const int c10 = cb | ((1 ^ F16) << 4) | ((0 ^ F32) << 5);
  const int c11 = cb | ((1 ^ F16) << 4) | ((1 ^ F32) << 5);
  v2f w00[8], w01[8], w10[8], w11[8];
#pragma unroll
  for (int s = 0; s < 8; ++s) {
    const int i0 = gcal[2 * s] * UNITS, i1 = gcal[2 * s + 1] * UNITS;
    float t00 = -2.f * SC * Whh[i0 + c00], t01 = -2.f * SC * Whh[i1 + c00];
    float t10 = -2.f * SC * Whh[i0 + c01], t11 = -2.f * SC * Whh[i1 + c01];
    float t20 = -2.f * SC * Whh[i0 + c10], t21 = -2.f * SC * Whh[i1 + c10];
    float t30 = -2.f * SC * Whh[i0 + c11], t31 = -2.f * SC * Whh[i1 + c11];
    asm volatile("" : "+v"(t00), "+v"(t01), "+v"(t10), "+v"(t11));
    asm volatile("" : "+v"(t20), "+v"(t21), "+v"(t30), "+v"(t31));
    w00[s].x = t00; w00[s].y = t01;  w01[s].x = t10; w01[s].y = t11;
    w10[s].x = t20; w10[s].y = t21;  w11[s].x = t30; w11[s].y = t31;
  }

  const int* trow = tok + (long)row * SEQ;

  float r = 0.5f;  // h = 0  <=>  r = 0.5

  // Uniform token ring (scalar loads): tkc = token(t+2) at iter t.
  int tkc = trow[2], tkn = trow[3];
  // P-value ring: a0 = row(t), a1 = row(t+1).
  float a0 = P[(long)trow[0] * UNITS + lane];
  float a1 = P[(long)trow[1] * UNITS + lane];

#pragma unroll 4
  for (int t = 0; t < SEQ; ++t) {
    float a_cur = a0;
    a0 = a1;
    a1 = P[(long)tkc * UNITS + lane];   // row t+2 (dist-2: latency covered)
    const int nidx = (t + 4 < SEQ) ? t + 4 : SEQ - 1;  // uniform clamp
    tkc = tkn; tkn = trow[nidx];

    // ---- in-register all-gather of r across own 16-lane row ----
    int gi[16];
    GATHER_ROW(__float_as_int(r), gi);

    // ---- 4 parity-assigned partials, 8-deep pk_fma chains ----
    v2f q00 = {0.f, 0.f}, q01 = {0.f, 0.f}, q10 = {0.f, 0.f}, q11 = {0.f, 0.f};
#pragma unroll
    for (int s = 0; s < 8; ++s) {
      v2f gp;
      gp.x = __int_as_float(gi[2 * s]);
      gp.y = __int_as_float(gi[2 * s + 1]);
      q00 += gp * w00[s];
      q01 += gp * w01[s];
      q10 += gp * w10[s];
      q11 += gp * w11[s];
    }
    float p00 = q00.x + q00.y;   // partial (j=0,k=0)
    float p01 = q01.x + q01.y;   // partial (j=0,k=1)
    float p10 = q10.x + q10.y;   // partial (j=1,k=0)
    float p11 = q11.x + q11.y;   // partial (j=1,k=1)

    // ---- selection-free combine (r5-proven; vdst slot = j/k = 1), then
    // fold the precomputed input term a (own column) once at the end ----
    float g0 = swadd16(p10, p00);      // halfsum, col bit5 = 0^F32
    float g1 = swadd16(p11, p01);      // halfsum, col bit5 = 1^F32
    float yv = swadd32(g1, g0) + a_cur;  // = SC * 2s(t+1)

    // r = 1/(e^{2s}+1);  e^{2s} = 2^yv (SC prescale)
    r = __builtin_amdgcn_rcpf(__builtin_amdgcn_exp2f(yv) + 1.f);
  }

  // h = 1 - 2r (once); out[row] = sigmoid(sum_j h[j]*Wout[j] + bout)
  float h = __builtin_fmaf(-2.f, r, 1.f);
  float p = h * Wout[lane];
#pragma unroll
  for (int off = 32; off > 0; off >>= 1) p += __shfl_xor(p, off);
  if (lane == 0) out[row] = 1.f / (1.f + __expf(-(p + bout[0])));
}

extern "C" void kernel_launch(void* const* d_in, const int* in_sizes, int n_in,
                              void* d_out, int out_size, void* d_ws, size_t ws_size,
                              hipStream_t stream) {
  const int*   tok  = (const int*)  d_in[0];  // [BATCH, SEQ] int32
  const float* emb  = (const float*)d_in[1];  // [VOCAB, EMB]
  const float* Wxh  = (const float*)d_in[2];  // [EMB, UNITS]
  const float* Whh  = (const float*)d_in[3];  // [UNITS, UNITS]
  const float* bias = (const float*)d_in[4];  // [UNITS]
  const float* Wout = (const float*)d_in[5];  // [UNITS, 1]
  const float* bout = (const float*)d_in[6];  // [1]
  float* out = (float*)d_out;                 // [BATCH, 1] fp32

  float* P = (float*)d_ws;                    // VOCAB*UNITS fp32 = 256 KB

  proj_kernel<<<VOCAB, 64, 0, stream>>>(emb, Wxh, bias, Whh, P);
  scan_kernel<<<BATCH, 64, 0, stream>>>(tok, P, Whh, Wout, bout, out);
}